// Round 13
// baseline (259.978 us; speedup 1.0000x reference)
//
#include <hip/hip_runtime.h>
#include <stdint.h>

typedef unsigned short u16;
typedef __attribute__((ext_vector_type(4))) unsigned short u16x4;
typedef __attribute__((ext_vector_type(8))) short s16x8;   // 8 bf16 (MFMA A/B frag)
typedef __attribute__((ext_vector_type(2))) float f32x2;
typedef __attribute__((ext_vector_type(4))) float f32x4;   // MFMA C/D frag
typedef __attribute__((ext_vector_type(4), aligned(4))) float f32x4u;  // loads only

#define NROWS 100000
#define RPB   32
#define NBLK  (NROWS / RPB)   // 3125 exact
#define NTHR  1024

// LDS pitches (elements); per-row-group strides = 16*pitch
#define PF   488
#define PS   360
#define PH   136
#define PD   232
#define PAB  484
#define PIF  132
#define FIN_RG  (16 * PF)
#define SCB_RG  (16 * PS)
#define HB_RG   (16 * PH)
#define DOT_RG  (16 * PD)
#define AOUT_RG (16 * PAB)
#define INN_RG  (16 * PIF)

// LDS arena (bytes). Overlays: fin(S1-S2)/aout(S5-S6); scb(S1-S4)/inner(S5-S6).
#define OFF_FIN   0        // 2*15616 = 31232  (aout: 2*15488 = 30976)
#define OFF_AOUT  0
#define OFF_SCB   31232    // 2*11520 = 23040  (inner: 2*8448 = 16896)
#define OFF_INNER 31232
#define OFF_DOTB  54272    // 2*7424 = 14848
#define OFF_HB    69120    // 2*4352 = 8704
#define OFF_BCOM  77824    // 864*2  = 1728
#define ARENA_SZ  79552    // -> 2 blocks/CU (LDS); 32 waves/CU if VGPR<=64

// packed-weight bases (elements) in d_ws (bf16 after pack)
#define B_UW0 0
#define B_UW1 16384
#define B_UW2 20480
#define B_VW0 21504
#define B_VW1 37888
#define B_VW2 41984
#define B_DW  43008
#define B_W1  71680
#define B_W2  116736
#define PACK_TOT 178176

__device__ inline float bf2f(u16 u) {
    union { uint32_t i; float f; } v; v.i = (uint32_t)u << 16; return v.f;
}
__device__ inline u16 f2bf(float f) {   // 1-op RNE via packed convert
    uint32_t d; asm("v_cvt_pk_bf16_f32 %0, %1, %1" : "=v"(d) : "v"(f)); return (u16)d;
}
__device__ inline uint32_t cvtpk(float lo, float hi) {
    uint32_t d; asm("v_cvt_pk_bf16_f32 %0, %1, %2" : "=v"(d) : "v"(lo), "v"(hi)); return d;
}
__device__ inline float wsum32(float v) {
    #pragma unroll
    for (int m = 16; m >= 1; m >>= 1) v += __shfl_xor(v, m);
    return v;
}

struct Ptrs {
    const float *xs, *xp, *lng, *lnb, *o3w, *o3b;
    const float *Uw0, *Uw1, *Uw2, *Ub0, *Vw0, *Vw1, *Vw2, *Vb0;
    const float *dw, *w1, *b1, *w2, *b2;
    const u16 *ws;
    float *out;
};

// Load KS B-fragments for one 16-col tile into registers (reused across row-groups).
template<int KS, bool PACKED>
__device__ inline void load_b(const void* W, int D, int tile, int lane, s16x8* bfr)
{
    #pragma unroll
    for (int ks = 0; ks < KS; ++ks) {
        if (PACKED) {
            bfr[ks] = *(const s16x8*)((const u16*)W + (((size_t)tile * KS + ks) * 64 + (size_t)lane) * 8);
        } else {
            union { u16 u[8]; s16x8 v; } bb;
            const int k0 = ks * 32 + ((lane >> 4) << 3), o = tile * 16 + (lane & 15);
            #pragma unroll
            for (int j = 0; j < 8; ++j)
                bb.u[j] = f2bf(((const float*)W)[(size_t)(k0 + j) * D + o]);
            bfr[ks] = bb.v;
        }
    }
}

// Accumulate one 16x16 tile from LDS A against pre-loaded B frags.
template<int KS>
__device__ inline f32x4 acc_ab(const u16* A, int pitchA, int lane, const s16x8* bfr)
{
    f32x4 acc = {0.f, 0.f, 0.f, 0.f};
    const u16* arow = A + (lane & 15) * pitchA + (lane >> 4) * 8;
    #pragma unroll
    for (int ks = 0; ks < KS; ++ks) {
        s16x8 a = *(const s16x8*)(arow + ks * 32);
        acc = __builtin_amdgcn_mfma_f32_16x16x32_bf16(a, bfr[ks], acc, 0, 0, 0);
    }
    return acc;
}

__global__ void pack_weights(Ptrs P, u16* ws)
{
    const int gid = blockIdx.x * 256 + threadIdx.x;
    if (gid >= PACK_TOT) return;
    const int  base[10] = {B_UW0, B_UW1, B_UW2, B_VW0, B_VW1, B_VW2, B_DW, B_W1, B_W2, PACK_TOT};
    const int  Kd[9]    = {128, 64, 32, 128, 64, 32, 224, 352, 128};
    const float* srcs[9] = {P.Uw0, P.Uw1, P.Uw2, P.Vw0, P.Vw1, P.Vw2, P.dw, P.w1, P.w2};
    const int  Dstride[9] = {128, 64, 32, 128, 64, 32, 128, 128, 480};
    int m = 0;
    for (int i = 1; i < 9; ++i) if (gid >= base[i]) m = i;
    const int e = gid - base[m];
    const int j = e & 7, lane = (e >> 3) & 63, tk = e >> 9;
    const int Ks = Kd[m] >> 5;
    const int ks = tk % Ks, tile = tk / Ks;
    const int k = ks * 32 + ((lane >> 4) << 3) + j;
    const int o = tile * 16 + (lane & 15);
    ws[gid] = f2bf(srcs[m][(size_t)k * Dstride[m] + o]);
}

// ---------------- stage 1: LN + O3 layernorm; one half-wave per row (32 rows) ----------------
__device__ inline void stage1_core(const Ptrs& P, u16* fin0, u16* scb0, int tid, int row0)
{
    const int rr = tid >> 5, l32 = tid & 31;   // rr 0..31
    const size_t row = (size_t)(row0 + rr);
    u16* finr = fin0 + (rr >> 4) * FIN_RG + (rr & 15) * PF;
    u16* scbr = scb0 + (rr >> 4) * SCB_RG + (rr & 15) * PS;
    const float* xsf = P.xs + row * 128;
    const float* xpf = P.xp + row * 480;
    {   // scalar layernorm -> scbr[0..127]
        f32x4 u = *(const f32x4*)(xsf + l32 * 4);
        float s  = u[0] + u[1] + u[2] + u[3];
        float s2 = u[0]*u[0] + u[1]*u[1] + u[2]*u[2] + u[3]*u[3];
        s = wsum32(s); s2 = wsum32(s2);
        const float mu = s * (1.f / 128.f);
        const float rs = 1.f / sqrtf(s2 * (1.f / 128.f) - mu * mu + 1e-5f);
        const int c = l32 * 4;
        float t[4];
        #pragma unroll
        for (int j2 = 0; j2 < 4; ++j2)
            t[j2] = (u[j2] - mu) * rs * P.lng[c + j2] + P.lnb[c + j2];
        *(uint32_t*)(scbr + c)     = cvtpk(t[0], t[1]);
        *(uint32_t*)(scbr + c + 2) = cvtpk(t[2], t[3]);
    }
    {   // s0 O3-LN -> finr[0..127]
        f32x4 u = *(const f32x4*)(xpf + l32 * 4);
        float s  = u[0] + u[1] + u[2] + u[3];
        float s2 = u[0]*u[0] + u[1]*u[1] + u[2]*u[2] + u[3]*u[3];
        s = wsum32(s); s2 = wsum32(s2);
        const float mu = s * (1.f / 128.f);
        const float rs = 1.f / sqrtf(s2 * (1.f / 128.f) - mu * mu + 1e-5f);
        const int c = l32 * 4;
        float t[4];
        #pragma unroll
        for (int j2 = 0; j2 < 4; ++j2)
            t[j2] = (u[j2] - mu) * rs * P.o3w[c + j2] + P.o3b[c + j2];
        *(uint32_t*)(finr + c)     = cvtpk(t[0], t[1]);
        *(uint32_t*)(finr + c + 2) = cvtpk(t[2], t[3]);
    }
    {   // s1 (64 irreps x 3) -> finr[128 + k*64 + i]
        const int cb = l32 * 6;
        f32x4u a = *(const f32x4u*)(xpf + 128 + cb);
        f32x2  b = *(const f32x2*)(xpf + 128 + cb + 4);
        float w[6] = {a[0], a[1], a[2], a[3], b[0], b[1]};
        float ss = 0.f;
        #pragma unroll
        for (int j2 = 0; j2 < 6; ++j2) ss += w[j2] * w[j2];
        ss = wsum32(ss);
        const float rs = 1.f / sqrtf(ss * (1.f / 192.f) + 1e-5f);
        #pragma unroll
        for (int j2 = 0; j2 < 6; ++j2) {
            const int c = cb + j2, i = c / 3, k = c - 3 * i;
            finr[128 + k * 64 + i] = f2bf(w[j2] * rs * P.o3w[128 + i]);
        }
    }
    {   // s2 (32 irreps x 5) -> finr[320 + k*32 + i]
        const int cb = l32 * 5;
        f32x4u a = *(const f32x4u*)(xpf + 320 + cb);
        float w[5] = {a[0], a[1], a[2], a[3], xpf[320 + cb + 4]};
        float ss = 0.f;
        #pragma unroll
        for (int j2 = 0; j2 < 5; ++j2) ss += w[j2] * w[j2];
        ss = wsum32(ss);
        const float rs = 1.f / sqrtf(ss * (1.f / 160.f) + 1e-5f);
        #pragma unroll
        for (int j2 = 0; j2 < 5; ++j2) {
            const int c = cb + j2, i = c / 5, k = c - 5 * i;
            finr[320 + k * 32 + i] = f2bf(w[j2] * rs * P.o3w[192 + i]);
        }
    }
}

template<bool PACKED>
__global__ __launch_bounds__(NTHR) void xpainn_main(Ptrs P)
{
    __shared__ __align__(16) unsigned char arena[ARENA_SZ];
    u16*   fin    = (u16*)(arena + OFF_FIN);
    u16*   aoutB  = (u16*)(arena + OFF_AOUT);
    u16*   scb    = (u16*)(arena + OFF_SCB);
    float* innerF = (float*)(arena + OFF_INNER);
    u16*   dotb   = (u16*)(arena + OFF_DOTB);
    u16*   hb     = (u16*)(arena + OFF_HB);
    u16*   bcom   = (u16*)(arena + OFF_BCOM);    // bf16 [Ub0 | Vb0 | b1 | b2(480)]

    const int tid = threadIdx.x;
    const int lane = tid & 63, wave = tid >> 6;   // wave 0..15
    const int r = lane & 15, g = lane >> 4;
    const int row0 = blockIdx.x * RPB;

    // biases -> LDS bf16
    for (int i = tid; i < 864; i += NTHR) {
        const float* src; int off;
        if (i < 128)      { src = P.Ub0; off = i; }
        else if (i < 256) { src = P.Vb0; off = i - 128; }
        else if (i < 384) { src = P.b1;  off = i - 256; }
        else              { src = P.b2;  off = i - 384; }
        bcom[i] = f2bf(src[off]);
    }
    stage1_core(P, fin, scb, tid, row0);
    __syncthreads();

    // ---------------- S2: U,V O3-linears; wave-specialized roles ----------------
    // w 0-7: l0 tile w (u0r).  w 8-11: l1 tile w-8 (uxr).  w 12-13: l2 tile w-12 (uxr).
    float u0r[2][4];       // l0 U (persist to S5; waves 0-7)
    float uxr[2][5][4];    // l1 (3 ch) / l2 (5 ch) U (persist to S5; waves 8-13)
    if (wave < 8) {
        s16x8 bU[4], bV[4];
        load_b<4, PACKED>(PACKED ? (const void*)(P.ws + B_UW0) : (const void*)P.Uw0, 128, wave, lane, bU);
        load_b<4, PACKED>(PACKED ? (const void*)(P.ws + B_VW0) : (const void*)P.Vw0, 128, wave, lane, bV);
        const int o = wave * 16 + r;
        const float bu = bf2f(bcom[o]), bv = bf2f(bcom[128 + o]);
        #pragma unroll
        for (int rg = 0; rg < 2; ++rg) {
            f32x4 au = acc_ab<4>(fin + rg * FIN_RG, PF, lane, bU);
            f32x4 av = acc_ab<4>(fin + rg * FIN_RG, PF, lane, bV);
            u16* scbR = scb + rg * SCB_RG;
            u16* dotR = dotb + rg * DOT_RG;
            #pragma unroll
            for (int q = 0; q < 4; ++q) {
                const float U = au[q] * 0.08838834764831845f + bu;
                const float V = av[q] * 0.08838834764831845f + bv;
                u0r[rg][q] = U;
                const int lrow = g * 4 + q;
                scbR[lrow * PS + 128 + o] = f2bf(fabsf(V));
                dotR[lrow * PD + o]       = f2bf(U * V);
            }
        }
    } else if (wave < 12) {         // l1: tile tt = wave-8, 3 channels, K=64
        const int tt = wave - 8, o = tt * 16 + r;
        float sv[2][4] = {{0.f,0.f,0.f,0.f},{0.f,0.f,0.f,0.f}};
        float suv[2][4] = {{0.f,0.f,0.f,0.f},{0.f,0.f,0.f,0.f}};
        #pragma unroll
        for (int ch = 0; ch < 3; ++ch) {
            s16x8 bU[2], bV[2];
            load_b<2, PACKED>(PACKED ? (const void*)(P.ws + B_UW1) : (const void*)P.Uw1, 64, tt, lane, bU);
            load_b<2, PACKED>(PACKED ? (const void*)(P.ws + B_VW1) : (const void*)P.Vw1, 64, tt, lane, bV);
            #pragma unroll
            for (int rg = 0; rg < 2; ++rg) {
                f32x4 au = acc_ab<2>(fin + rg * FIN_RG + 128 + 64 * ch, PF, lane, bU);
                f32x4 av = acc_ab<2>(fin + rg * FIN_RG + 128 + 64 * ch, PF, lane, bV);
                #pragma unroll
                for (int q = 0; q < 4; ++q) {
                    const float U = au[q] * 0.125f, V = av[q] * 0.125f;
                    uxr[rg][ch][q] = U; sv[rg][q] += V * V; suv[rg][q] += U * V;
                }
            }
        }
        #pragma unroll
        for (int rg = 0; rg < 2; ++rg) {
            #pragma unroll
            for (int q = 0; q < 4; ++q) {
                const int lrow = g * 4 + q;
                (scb + rg * SCB_RG)[lrow * PS + 256 + o]  = f2bf(sqrtf(sv[rg][q]));
                (dotb + rg * DOT_RG)[lrow * PD + 128 + o] = f2bf(suv[rg][q] * 0.5773502691896258f);
            }
        }
    } else if (wave < 14) {         // l2: tile tt = wave-12, 5 channels, K=32
        const int tt = wave - 12, o = tt * 16 + r;
        float sv[2][4] = {{0.f,0.f,0.f,0.f},{0.f,0.f,0.f,0.f}};
        float suv[2][4] = {{0.f,0.f,0.f,0.f},{0.f,0.f,0.f,0.f}};
        #pragma unroll
        for (int ch = 0; ch < 5; ++ch) {
            s16x8 bU[1], bV[1];
            load_b<1, PACKED>(PACKED ? (const void*)(P.ws + B_UW2) : (const void*)P.Uw2, 32, tt, lane, bU);
            load_b<1, PACKED>(PACKED ? (const void*)(P.ws + B_VW2) : (const void*)P.Vw2, 32, tt, lane, bV);
            #pragma unroll
            for (int rg = 0; rg < 2; ++rg) {
                f32x4 au = acc_ab<1>(fin + rg * FIN_RG + 320 + 32 * ch, PF, lane, bU);
                f32x4 av = acc_ab<1>(fin + rg * FIN_RG + 320 + 32 * ch, PF, lane, bV);
                #pragma unroll
                for (int q = 0; q < 4; ++q) {
                    const float U = au[q] * 0.17677669529663687f, V = av[q] * 0.17677669529663687f;
                    uxr[rg][ch][q] = U; sv[rg][q] += V * V; suv[rg][q] += U * V;
                }
            }
        }
        #pragma unroll
        for (int rg = 0; rg < 2; ++rg) {
            #pragma unroll
            for (int q = 0; q < 4; ++q) {
                const int lrow = g * 4 + q;
                (scb + rg * SCB_RG)[lrow * PS + 320 + o]  = f2bf(sqrtf(sv[rg][q]));
                (dotb + rg * DOT_RG)[lrow * PD + 192 + o] = f2bf(suv[rg][q] * 0.4472135954999579f);
            }
        }
    }
    __syncthreads();

    // ---------------- S4: mlp1 + silu; one (tile, rg) task per wave ----------------
    {
        const int tile = wave & 7, rg = wave >> 3;
        s16x8 bfr[11];
        load_b<11, PACKED>(PACKED ? (const void*)(P.ws + B_W1) : (const void*)P.w1, 128, tile, lane, bfr);
        f32x4 acc = acc_ab<11>(scb + rg * SCB_RG, PS, lane, bfr);
        const int o = tile * 16 + r;
        const float bv = bf2f(bcom[256 + o]);
        #pragma unroll
        for (int q = 0; q < 4; ++q) {
            float x = acc[q] + bv;
            hb[rg * HB_RG + (g * 4 + q) * PH + o] = f2bf(x / (1.f + expf(-x)));
        }
    }
    __syncthreads();

    // ---------------- S5: mlp2 + inner with fused spherical residual ----------------
    // avv0 tile w owned by wave w (<8, has u0r); avv1 tile w owned by wave w (8..13, has uxr).
    if (wave < 8) {
        s16x8 bfr[4];
        load_b<4, PACKED>(PACKED ? (const void*)(P.ws + B_W2) : (const void*)P.w2, 480, wave, lane, bfr);
        const int o = wave * 16 + r;
        const float bv = bf2f(bcom[384 + o]);
        const size_t ob = (size_t)NROWS * 128;
        #pragma unroll
        for (int rg = 0; rg < 2; ++rg) {
            f32x4 acc = acc_ab<4>(hb + rg * HB_RG, PH, lane, bfr);
            #pragma unroll
            for (int q = 0; q < 4; ++q) {
                const float avv0 = acc[q] + bv;
                const size_t gr = (size_t)(row0 + rg * 16 + g * 4 + q) * 480;
                P.out[ob + gr + o] = P.xp[gr + o] + u0r[rg][q] * avv0;
            }
        }
    } else if (wave < 14) {
        s16x8 bfr[4];
        load_b<4, PACKED>(PACKED ? (const void*)(P.ws + B_W2) : (const void*)P.w2, 480, wave, lane, bfr);
        const float bv = bf2f(bcom[384 + wave * 16 + r]);
        const size_t ob = (size_t)NROWS * 128;
        #pragma unroll
        for (int rg = 0; rg < 2; ++rg) {
            f32x4 acc = acc_ab<4>(hb + rg * HB_RG, PH, lane, bfr);
            if (wave < 12) {
                const int i = (wave - 8) * 16 + r;
                #pragma unroll
                for (int q = 0; q < 4; ++q) {
                    const float avv1 = acc[q] + bv;
                    const size_t gr = (size_t)(row0 + rg * 16 + g * 4 + q) * 480;
                    #pragma unroll
                    for (int ch = 0; ch < 3; ++ch) {
                        const size_t c = 128 + 3 * i + ch;
                        P.out[ob + gr + c] = P.xp[gr + c] + uxr[rg][ch][q] * avv1;
                    }
                }
            } else {
                const int i = (wave - 12) * 16 + r;
                #pragma unroll
                for (int q = 0; q < 4; ++q) {
                    const float avv1 = acc[q] + bv;
                    const size_t gr = (size_t)(row0 + rg * 16 + g * 4 + q) * 480;
                    #pragma unroll
                    for (int ch = 0; ch < 5; ++ch) {
                        const size_t c = 320 + 5 * i + ch;
                        P.out[ob + gr + c] = P.xp[gr + c] + uxr[rg][ch][q] * avv1;
                    }
                }
            }
        }
    } else {
        // waves 14,15: mlp2 tiles 14,15 (a_sv cols 224..255) -> aout
        s16x8 bfr[4];
        load_b<4, PACKED>(PACKED ? (const void*)(P.ws + B_W2) : (const void*)P.w2, 480, wave, lane, bfr);
        const int o = wave * 16 + r;
        const float bv = bf2f(bcom[384 + o]);
        #pragma unroll
        for (int rg = 0; rg < 2; ++rg) {
            f32x4 acc = acc_ab<4>(hb + rg * HB_RG, PH, lane, bfr);
            u16* aoutR = aoutB + rg * AOUT_RG;
            #pragma unroll
            for (int q = 0; q < 4; ++q)
                aoutR[(g * 4 + q) * PAB + o] = f2bf(acc[q] + bv);
        }
    }
    // remaining: mlp2 tiles 16..29 (a_sv/a_ss) and inner tiles 0..7; 22 tile-tasks over 16 waves
    for (int tt = wave; tt < 22; tt += 16) {
        if (tt < 14) {
            const int ti = 16 + tt;
            s16x8 bfr[4];
            load_b<4, PACKED>(PACKED ? (const void*)(P.ws + B_W2) : (const void*)P.w2, 480, ti, lane, bfr);
            const int o = ti * 16 + r;
            const float bv = bf2f(bcom[384 + o]);
            #pragma unroll
            for (int rg = 0; rg < 2; ++rg) {
                f32x4 acc = acc_ab<4>(hb + rg * HB_RG, PH, lane, bfr);
                u16* aoutR = aoutB + rg * AOUT_RG;
                #pragma unroll
                for (int q = 0; q < 4; ++q)
                    aoutR[(g * 4 + q) * PAB + o] = f2bf(acc[q] + bv);
            }
        } else {
            const int ti = tt - 14;   // inner tile 0..7
            s16x8 bfr[7];
            load_b<7, PACKED>(PACKED ? (const void*)(P.ws + B_DW) : (const void*)P.dw, 128, ti, lane, bfr);
            const int oo = ti * 16 + r;
            #pragma unroll
            for (int rg = 0; rg < 2; ++rg) {
                f32x4 acc = acc_ab<7>(dotb + rg * DOT_RG, PD, lane, bfr);
                float* innR = innerF + rg * INN_RG;
                #pragma unroll
                for (int q = 0; q < 4; ++q)
                    innR[(g * 4 + q) * PIF + oo] = acc[q];
            }
        }
    }
    __syncthreads();

    // ---------------- S6: scalar residual: out = xs + a_sv*inner + a_ss (1 iter/thread) ----
    {
        const int r2 = tid >> 5, c4 = (tid & 31) * 4;   // r2 0..31
        const u16*  aoutR = aoutB + (r2 >> 4) * AOUT_RG + (r2 & 15) * PAB;
        const float* innR = innerF + (r2 >> 4) * INN_RG + (r2 & 15) * PIF;
        const size_t gb = (size_t)(row0 + r2) * 128 + c4;
        const u16x4 asv = *(const u16x4*)(aoutR + 224 + c4);
        const u16x4 ass = *(const u16x4*)(aoutR + 352 + c4);
        const f32x4 inn = *(const f32x4*)(innR + c4);
        const f32x4 xs = *(const f32x4*)(P.xs + gb);
        f32x4 o;
        #pragma unroll
        for (int j = 0; j < 4; ++j) o[j] = xs[j] + bf2f(asv[j]) * inn[j] + bf2f(ass[j]);
        *(f32x4*)(P.out + gb) = o;
    }
}

extern "C" void kernel_launch(void* const* d_in, const int* in_sizes, int n_in,
                              void* d_out, int out_size, void* d_ws, size_t ws_size,
                              hipStream_t stream)
{
    Ptrs P;
    P.xs  = (const float*)d_in[0];  P.xp  = (const float*)d_in[1];
    P.lng = (const float*)d_in[2];  P.lnb = (const float*)d_in[3];
    P.o3w = (const float*)d_in[4];  P.o3b = (const float*)d_in[5];
    P.Uw0 = (const float*)d_in[6];  P.Uw1 = (const float*)d_in[7];
    P.Uw2 = (const float*)d_in[8];  P.Ub0 = (const float*)d_in[9];
    P.Vw0 = (const float*)d_in[10]; P.Vw1 = (const float*)d_in[11];
    P.Vw2 = (const float*)d_in[12]; P.Vb0 = (const float*)d_in[13];
    P.dw  = (const float*)d_in[14]; P.w1  = (const float*)d_in[15];
    P.b1  = (const float*)d_in[16]; P.w2  = (const float*)d_in[17];
    P.b2  = (const float*)d_in[18];
    P.ws  = (const u16*)d_ws;
    P.out = (float*)d_out;

    const bool packed = (ws_size >= (size_t)PACK_TOT * sizeof(u16));
    if (packed) {
        pack_weights<<<(PACK_TOT + 255) / 256, 256, 0, stream>>>(P, (u16*)d_ws);
        xpainn_main<true><<<NBLK, NTHR, 0, stream>>>(P);
    } else {
        xpainn_main<false><<<NBLK, NTHR, 0, stream>>>(P);
    }
}

// Round 14
// 220.029 us; speedup vs baseline: 1.1816x; 1.1816x over previous
//
#include <hip/hip_runtime.h>
#include <stdint.h>

typedef unsigned short u16;
typedef __attribute__((ext_vector_type(4))) unsigned short u16x4;
typedef __attribute__((ext_vector_type(8))) short s16x8;   // 8 bf16 (MFMA A/B frag)
typedef __attribute__((ext_vector_type(2))) float f32x2;
typedef __attribute__((ext_vector_type(4))) float f32x4;   // MFMA C/D frag
typedef __attribute__((ext_vector_type(4), aligned(4))) float f32x4u;  // loads only

#define NROWS 100000
#define RPB   32
#define NBLK  (NROWS / RPB)   // 3125 exact
#define NTHR  512

// LDS pitches (elements); per-row-group strides = 16*pitch
#define PF   488
#define PS   360
#define PH   136
#define PD   232
#define PAB  484
#define PIF  132
#define FIN_RG  (16 * PF)
#define SCB_RG  (16 * PS)
#define HB_RG   (16 * PH)
#define DOT_RG  (16 * PD)
#define AOUT_RG (16 * PAB)
#define INN_RG  (16 * PIF)

// LDS arena (bytes). Overlays: fin(S1-S2)/aout(S5-S6); scb(S1-S4)/inner(S5-S6).
#define OFF_FIN   0        // 2*15616 = 31232  (aout: 2*15488 = 30976)
#define OFF_AOUT  0
#define OFF_SCB   31232    // 2*11520 = 23040  (inner: 2*8448 = 16896)
#define OFF_INNER 31232
#define OFF_DOTB  54272    // 2*7424 = 14848
#define OFF_HB    69120    // 2*4352 = 8704
#define OFF_BCOM  77824    // 864*2  = 1728
#define ARENA_SZ  79552    // -> 2 blocks/CU

// packed-weight bases (elements) in d_ws (bf16 after pack)
#define B_UW0 0
#define B_UW1 16384
#define B_UW2 20480
#define B_VW0 21504
#define B_VW1 37888
#define B_VW2 41984
#define B_DW  43008
#define B_W1  71680
#define B_W2  116736
#define PACK_TOT 178176

__device__ inline float bf2f(u16 u) {
    union { uint32_t i; float f; } v; v.i = (uint32_t)u << 16; return v.f;
}
__device__ inline u16 f2bf(float f) {   // 1-op RNE via packed convert
    uint32_t d; asm("v_cvt_pk_bf16_f32 %0, %1, %1" : "=v"(d) : "v"(f)); return (u16)d;
}
__device__ inline uint32_t cvtpk(float lo, float hi) {
    uint32_t d; asm("v_cvt_pk_bf16_f32 %0, %1, %2" : "=v"(d) : "v"(lo), "v"(hi)); return d;
}
__device__ inline float wsum32(float v) {
    #pragma unroll
    for (int m = 16; m >= 1; m >>= 1) v += __shfl_xor(v, m);
    return v;
}

struct Ptrs {
    const float *xs, *xp, *lng, *lnb, *o3w, *o3b;
    const float *Uw0, *Uw1, *Uw2, *Ub0, *Vw0, *Vw1, *Vw2, *Vb0;
    const float *dw, *w1, *b1, *w2, *b2;
    const u16 *ws;
    float *out;
};

// Load KS B-fragments for one 16-col tile into registers (reused across row-groups).
template<int KS, bool PACKED>
__device__ inline void load_b(const void* W, int D, int tile, int lane, s16x8* bfr)
{
    #pragma unroll
    for (int ks = 0; ks < KS; ++ks) {
        if (PACKED) {
            bfr[ks] = *(const s16x8*)((const u16*)W + (((size_t)tile * KS + ks) * 64 + (size_t)lane) * 8);
        } else {
            union { u16 u[8]; s16x8 v; } bb;
            const int k0 = ks * 32 + ((lane >> 4) << 3), o = tile * 16 + (lane & 15);
            #pragma unroll
            for (int j = 0; j < 8; ++j)
                bb.u[j] = f2bf(((const float*)W)[(size_t)(k0 + j) * D + o]);
            bfr[ks] = bb.v;
        }
    }
}

// Accumulate one 16x16 tile from LDS A against pre-loaded B frags.
template<int KS>
__device__ inline f32x4 acc_ab(const u16* A, int pitchA, int lane, const s16x8* bfr)
{
    f32x4 acc = {0.f, 0.f, 0.f, 0.f};
    const u16* arow = A + (lane & 15) * pitchA + (lane >> 4) * 8;
    #pragma unroll
    for (int ks = 0; ks < KS; ++ks) {
        s16x8 a = *(const s16x8*)(arow + ks * 32);
        acc = __builtin_amdgcn_mfma_f32_16x16x32_bf16(a, bfr[ks], acc, 0, 0, 0);
    }
    return acc;
}

__global__ void pack_weights(Ptrs P, u16* ws)
{
    const int gid = blockIdx.x * 256 + threadIdx.x;
    if (gid >= PACK_TOT) return;
    const int  base[10] = {B_UW0, B_UW1, B_UW2, B_VW0, B_VW1, B_VW2, B_DW, B_W1, B_W2, PACK_TOT};
    const int  Kd[9]    = {128, 64, 32, 128, 64, 32, 224, 352, 128};
    const float* srcs[9] = {P.Uw0, P.Uw1, P.Uw2, P.Vw0, P.Vw1, P.Vw2, P.dw, P.w1, P.w2};
    const int  Dstride[9] = {128, 64, 32, 128, 64, 32, 128, 128, 480};
    int m = 0;
    for (int i = 1; i < 9; ++i) if (gid >= base[i]) m = i;
    const int e = gid - base[m];
    const int j = e & 7, lane = (e >> 3) & 63, tk = e >> 9;
    const int Ks = Kd[m] >> 5;
    const int ks = tk % Ks, tile = tk / Ks;
    const int k = ks * 32 + ((lane >> 4) << 3) + j;
    const int o = tile * 16 + (lane & 15);
    ws[gid] = f2bf(srcs[m][(size_t)k * Dstride[m] + o]);
}

// ---------------- stage 1: LN + O3 layernorm; half-wave handles rows hw, hw+16 ----------------
__device__ inline void stage1_core(const Ptrs& P, u16* fin0, u16* scb0, int tid, int row0)
{
    const int hw = tid >> 5, l32 = tid & 31;
    #pragma unroll
    for (int rg = 0; rg < 2; ++rg) {
        const int rr = hw + rg * 16;
        const size_t row = (size_t)(row0 + rr);
        u16* finr = fin0 + rg * FIN_RG + hw * PF;
        u16* scbr = scb0 + rg * SCB_RG + hw * PS;
        const float* xsf = P.xs + row * 128;
        const float* xpf = P.xp + row * 480;
        {   // scalar layernorm -> scbr[0..127]
            f32x4 u = *(const f32x4*)(xsf + l32 * 4);
            float s  = u[0] + u[1] + u[2] + u[3];
            float s2 = u[0]*u[0] + u[1]*u[1] + u[2]*u[2] + u[3]*u[3];
            s = wsum32(s); s2 = wsum32(s2);
            const float mu = s * (1.f / 128.f);
            const float rs = 1.f / sqrtf(s2 * (1.f / 128.f) - mu * mu + 1e-5f);
            const int c = l32 * 4;
            float t[4];
            #pragma unroll
            for (int j2 = 0; j2 < 4; ++j2)
                t[j2] = (u[j2] - mu) * rs * P.lng[c + j2] + P.lnb[c + j2];
            *(uint32_t*)(scbr + c)     = cvtpk(t[0], t[1]);
            *(uint32_t*)(scbr + c + 2) = cvtpk(t[2], t[3]);
        }
        {   // s0 O3-LN -> finr[0..127]
            f32x4 u = *(const f32x4*)(xpf + l32 * 4);
            float s  = u[0] + u[1] + u[2] + u[3];
            float s2 = u[0]*u[0] + u[1]*u[1] + u[2]*u[2] + u[3]*u[3];
            s = wsum32(s); s2 = wsum32(s2);
            const float mu = s * (1.f / 128.f);
            const float rs = 1.f / sqrtf(s2 * (1.f / 128.f) - mu * mu + 1e-5f);
            const int c = l32 * 4;
            float t[4];
            #pragma unroll
            for (int j2 = 0; j2 < 4; ++j2)
                t[j2] = (u[j2] - mu) * rs * P.o3w[c + j2] + P.o3b[c + j2];
            *(uint32_t*)(finr + c)     = cvtpk(t[0], t[1]);
            *(uint32_t*)(finr + c + 2) = cvtpk(t[2], t[3]);
        }
        {   // s1 (64 irreps x 3) -> finr[128 + k*64 + i]
            const int cb = l32 * 6;
            f32x4u a = *(const f32x4u*)(xpf + 128 + cb);
            f32x2  b = *(const f32x2*)(xpf + 128 + cb + 4);
            float w[6] = {a[0], a[1], a[2], a[3], b[0], b[1]};
            float ss = 0.f;
            #pragma unroll
            for (int j2 = 0; j2 < 6; ++j2) ss += w[j2] * w[j2];
            ss = wsum32(ss);
            const float rs = 1.f / sqrtf(ss * (1.f / 192.f) + 1e-5f);
            #pragma unroll
            for (int j2 = 0; j2 < 6; ++j2) {
                const int c = cb + j2, i = c / 3, k = c - 3 * i;
                finr[128 + k * 64 + i] = f2bf(w[j2] * rs * P.o3w[128 + i]);
            }
        }
        {   // s2 (32 irreps x 5) -> finr[320 + k*32 + i]
            const int cb = l32 * 5;
            f32x4u a = *(const f32x4u*)(xpf + 320 + cb);
            float w[5] = {a[0], a[1], a[2], a[3], xpf[320 + cb + 4]};
            float ss = 0.f;
            #pragma unroll
            for (int j2 = 0; j2 < 5; ++j2) ss += w[j2] * w[j2];
            ss = wsum32(ss);
            const float rs = 1.f / sqrtf(ss * (1.f / 160.f) + 1e-5f);
            #pragma unroll
            for (int j2 = 0; j2 < 5; ++j2) {
                const int c = cb + j2, i = c / 5, k = c - 5 * i;
                finr[320 + k * 32 + i] = f2bf(w[j2] * rs * P.o3w[192 + i]);
            }
        }
    }
}

template<bool PACKED>
__global__ __launch_bounds__(NTHR, 4) void xpainn_main(Ptrs P)
{
    __shared__ __align__(16) unsigned char arena[ARENA_SZ];
    u16*   fin    = (u16*)(arena + OFF_FIN);
    u16*   aoutB  = (u16*)(arena + OFF_AOUT);
    u16*   scb    = (u16*)(arena + OFF_SCB);
    float* innerF = (float*)(arena + OFF_INNER);
    u16*   dotb   = (u16*)(arena + OFF_DOTB);
    u16*   hb     = (u16*)(arena + OFF_HB);
    u16*   bcom   = (u16*)(arena + OFF_BCOM);    // bf16 [Ub0 | Vb0 | b1 | b2(480)]

    const int tid = threadIdx.x;
    const int lane = tid & 63, wave = tid >> 6;
    const int r = lane & 15, g = lane >> 4;
    const int row0 = blockIdx.x * RPB;

    // biases -> LDS bf16
    for (int i = tid; i < 864; i += NTHR) {
        const float* src; int off;
        if (i < 128)      { src = P.Ub0; off = i; }
        else if (i < 256) { src = P.Vb0; off = i - 128; }
        else if (i < 384) { src = P.b1;  off = i - 256; }
        else              { src = P.b2;  off = i - 384; }
        bcom[i] = f2bf(src[off]);
    }
    stage1_core(P, fin, scb, tid, row0);
    __syncthreads();

    // ---------------- S2: U,V O3-linears, B in regs across both row-groups ----------------
    float u0r[2][4];       // l0 U (persist to S5-fused output)
    float uxr[2][5][4];    // l1 (3 ch) / l2 (5 ch) U
    {
        s16x8 bU[4], bV[4];
        load_b<4, PACKED>(PACKED ? (const void*)(P.ws + B_UW0) : (const void*)P.Uw0, 128, wave, lane, bU);
        load_b<4, PACKED>(PACKED ? (const void*)(P.ws + B_VW0) : (const void*)P.Vw0, 128, wave, lane, bV);
        const int o = wave * 16 + r;
        const float bu = bf2f(bcom[o]), bv = bf2f(bcom[128 + o]);
        #pragma unroll
        for (int rg = 0; rg < 2; ++rg) {
            f32x4 au = acc_ab<4>(fin + rg * FIN_RG, PF, lane, bU);
            f32x4 av = acc_ab<4>(fin + rg * FIN_RG, PF, lane, bV);
            u16* scbR = scb + rg * SCB_RG;
            u16* dotR = dotb + rg * DOT_RG;
            #pragma unroll
            for (int q = 0; q < 4; ++q) {
                const float U = au[q] * 0.08838834764831845f + bu;
                const float V = av[q] * 0.08838834764831845f + bv;
                u0r[rg][q] = U;
                const int lrow = g * 4 + q;
                scbR[lrow * PS + 128 + o] = f2bf(fabsf(V));
                dotR[lrow * PD + o]       = f2bf(U * V);
            }
        }
    }
    if (wave < 4) {                 // l1: tile tt = wave, 3 channels, K=64
        const int tt = wave, o = tt * 16 + r;
        float sv[2][4] = {{0.f,0.f,0.f,0.f},{0.f,0.f,0.f,0.f}};
        float suv[2][4] = {{0.f,0.f,0.f,0.f},{0.f,0.f,0.f,0.f}};
        #pragma unroll
        for (int ch = 0; ch < 3; ++ch) {
            s16x8 bU[2], bV[2];
            load_b<2, PACKED>(PACKED ? (const void*)(P.ws + B_UW1) : (const void*)P.Uw1, 64, tt, lane, bU);
            load_b<2, PACKED>(PACKED ? (const void*)(P.ws + B_VW1) : (const void*)P.Vw1, 64, tt, lane, bV);
            #pragma unroll
            for (int rg = 0; rg < 2; ++rg) {
                f32x4 au = acc_ab<2>(fin + rg * FIN_RG + 128 + 64 * ch, PF, lane, bU);
                f32x4 av = acc_ab<2>(fin + rg * FIN_RG + 128 + 64 * ch, PF, lane, bV);
                #pragma unroll
                for (int q = 0; q < 4; ++q) {
                    const float U = au[q] * 0.125f, V = av[q] * 0.125f;
                    uxr[rg][ch][q] = U; sv[rg][q] += V * V; suv[rg][q] += U * V;
                }
            }
        }
        #pragma unroll
        for (int rg = 0; rg < 2; ++rg) {
            #pragma unroll
            for (int q = 0; q < 4; ++q) {
                const int lrow = g * 4 + q;
                (scb + rg * SCB_RG)[lrow * PS + 256 + o]  = f2bf(sqrtf(sv[rg][q]));
                (dotb + rg * DOT_RG)[lrow * PD + 128 + o] = f2bf(suv[rg][q] * 0.5773502691896258f);
            }
        }
    } else if (wave < 6) {          // l2: tile tt = wave-4, 5 channels, K=32
        const int tt = wave - 4, o = tt * 16 + r;
        float sv[2][4] = {{0.f,0.f,0.f,0.f},{0.f,0.f,0.f,0.f}};
        float suv[2][4] = {{0.f,0.f,0.f,0.f},{0.f,0.f,0.f,0.f}};
        #pragma unroll
        for (int ch = 0; ch < 5; ++ch) {
            s16x8 bU[1], bV[1];
            load_b<1, PACKED>(PACKED ? (const void*)(P.ws + B_UW2) : (const void*)P.Uw2, 32, tt, lane, bU);
            load_b<1, PACKED>(PACKED ? (const void*)(P.ws + B_VW2) : (const void*)P.Vw2, 32, tt, lane, bV);
            #pragma unroll
            for (int rg = 0; rg < 2; ++rg) {
                f32x4 au = acc_ab<1>(fin + rg * FIN_RG + 320 + 32 * ch, PF, lane, bU);
                f32x4 av = acc_ab<1>(fin + rg * FIN_RG + 320 + 32 * ch, PF, lane, bV);
                #pragma unroll
                for (int q = 0; q < 4; ++q) {
                    const float U = au[q] * 0.17677669529663687f, V = av[q] * 0.17677669529663687f;
                    uxr[rg][ch][q] = U; sv[rg][q] += V * V; suv[rg][q] += U * V;
                }
            }
        }
        #pragma unroll
        for (int rg = 0; rg < 2; ++rg) {
            #pragma unroll
            for (int q = 0; q < 4; ++q) {
                const int lrow = g * 4 + q;
                (scb + rg * SCB_RG)[lrow * PS + 320 + o]  = f2bf(sqrtf(sv[rg][q]));
                (dotb + rg * DOT_RG)[lrow * PD + 192 + o] = f2bf(suv[rg][q] * 0.4472135954999579f);
            }
        }
    }
    __syncthreads();

    // ---------------- S4: mlp1 + silu -> hb ----------------
    #pragma unroll
    for (int rg = 0; rg < 2; ++rg) {
        s16x8 bfr[11];
        load_b<11, PACKED>(PACKED ? (const void*)(P.ws + B_W1) : (const void*)P.w1, 128, wave, lane, bfr);
        f32x4 acc = acc_ab<11>(scb + rg * SCB_RG, PS, lane, bfr);
        const int o = wave * 16 + r;
        const float bv = bf2f(bcom[256 + o]);
        #pragma unroll
        for (int q = 0; q < 4; ++q) {
            float x = acc[q] + bv;
            hb[rg * HB_RG + (g * 4 + q) * PH + o] = f2bf(x / (1.f + expf(-x)));
        }
    }
    __syncthreads();

    // ---------------- S5: mlp2 + inner, with fused spherical residual ----------------
    // Tile->wave map: tile w (it0) and tile w+8 (it1) produce exactly the a_vv columns
    // whose U values this wave holds in registers -> spherical out needs no LDS a_vv
    // and no register persistence across barriers.
    {
        float avv0[2][4], avv1[2][4];
        {   // it0: ti = wave (a_vv cols 16w .. 16w+15, matches u0r)
            s16x8 bfr[4];
            load_b<4, PACKED>(PACKED ? (const void*)(P.ws + B_W2) : (const void*)P.w2, 480, wave, lane, bfr);
            const int o = wave * 16 + r;
            const float bv = bf2f(bcom[384 + o]);
            #pragma unroll
            for (int rg = 0; rg < 2; ++rg) {
                f32x4 acc = acc_ab<4>(hb + rg * HB_RG, PH, lane, bfr);
                #pragma unroll
                for (int q = 0; q < 4; ++q) avv0[rg][q] = acc[q] + bv;
            }
        }
        {   // it1: ti = wave+8 (waves 0-5: a_vv l1/l2 cols matching uxr; waves 6-7: a_sv part)
            const int ti = wave + 8;
            s16x8 bfr[4];
            load_b<4, PACKED>(PACKED ? (const void*)(P.ws + B_W2) : (const void*)P.w2, 480, ti, lane, bfr);
            const int o = ti * 16 + r;
            const float bv = bf2f(bcom[384 + o]);
            #pragma unroll
            for (int rg = 0; rg < 2; ++rg) {
                f32x4 acc = acc_ab<4>(hb + rg * HB_RG, PH, lane, bfr);
                if (wave < 6) {
                    #pragma unroll
                    for (int q = 0; q < 4; ++q) avv1[rg][q] = acc[q] + bv;
                } else {
                    u16* aoutR = aoutB + rg * AOUT_RG;
                    #pragma unroll
                    for (int q = 0; q < 4; ++q)
                        aoutR[(g * 4 + q) * PAB + o] = f2bf(acc[q] + bv);
                }
            }
        }
        // spherical residual: out = xp + U * a_vv   (all operands in registers)
        {
            const size_t ob = (size_t)NROWS * 128;
            #pragma unroll
            for (int rg = 0; rg < 2; ++rg) {
                const int o = wave * 16 + r;
                #pragma unroll
                for (int q = 0; q < 4; ++q) {
                    const size_t gr = (size_t)(row0 + rg * 16 + g * 4 + q) * 480;
                    P.out[ob + gr + o] = P.xp[gr + o] + u0r[rg][q] * avv0[rg][q];
                }
                if (wave < 4) {
                    const int i = wave * 16 + r;
                    #pragma unroll
                    for (int q = 0; q < 4; ++q) {
                        const size_t gr = (size_t)(row0 + rg * 16 + g * 4 + q) * 480;
                        #pragma unroll
                        for (int ch = 0; ch < 3; ++ch) {
                            const size_t c = 128 + 3 * i + ch;
                            P.out[ob + gr + c] = P.xp[gr + c] + uxr[rg][ch][q] * avv1[rg][q];
                        }
                    }
                } else if (wave < 6) {
                    const int i = (wave - 4) * 16 + r;
                    #pragma unroll
                    for (int q = 0; q < 4; ++q) {
                        const size_t gr = (size_t)(row0 + rg * 16 + g * 4 + q) * 480;
                        #pragma unroll
                        for (int ch = 0; ch < 5; ++ch) {
                            const size_t c = 320 + 5 * i + ch;
                            P.out[ob + gr + c] = P.xp[gr + c] + uxr[rg][ch][q] * avv1[rg][q];
                        }
                    }
                }
            }
        }
        // remaining tiles: mlp2 a_sv/a_ss (16..29) and inner (30..37)
        for (int ti = wave + 16; ti < 38; ti += 8) {
            if (ti < 30) {
                s16x8 bfr[4];
                load_b<4, PACKED>(PACKED ? (const void*)(P.ws + B_W2) : (const void*)P.w2, 480, ti, lane, bfr);
                const int o = ti * 16 + r;
                const float bv = bf2f(bcom[384 + o]);
                #pragma unroll
                for (int rg = 0; rg < 2; ++rg) {
                    f32x4 acc = acc_ab<4>(hb + rg * HB_RG, PH, lane, bfr);
                    u16* aoutR = aoutB + rg * AOUT_RG;
                    #pragma unroll
                    for (int q = 0; q < 4; ++q)
                        aoutR[(g * 4 + q) * PAB + o] = f2bf(acc[q] + bv);
                }
            } else {
                s16x8 bfr[7];
                load_b<7, PACKED>(PACKED ? (const void*)(P.ws + B_DW) : (const void*)P.dw, 128, ti - 30, lane, bfr);
                const int oo = (ti - 30) * 16 + r;
                #pragma unroll
                for (int rg = 0; rg < 2; ++rg) {
                    f32x4 acc = acc_ab<7>(dotb + rg * DOT_RG, PD, lane, bfr);
                    float* innR = innerF + rg * INN_RG;
                    #pragma unroll
                    for (int q = 0; q < 4; ++q)
                        innR[(g * 4 + q) * PIF + oo] = acc[q];
                }
            }
        }
    }
    __syncthreads();

    // ---------------- S6: scalar residual only ----------------
    #pragma unroll
    for (int it = 0; it < 2; ++it) {
        const int idx = tid + it * NTHR;            // 0..1023 = 32 rows x 32 groups
        const int r2 = idx >> 5, c4 = (idx & 31) * 4;
        const u16*  aoutR = aoutB + (r2 >> 4) * AOUT_RG + (r2 & 15) * PAB;
        const float* innR = innerF + (r2 >> 4) * INN_RG + (r2 & 15) * PIF;
        const size_t gb = (size_t)(row0 + r2) * 128 + c4;
        const u16x4 asv = *(const u16x4*)(aoutR + 224 + c4);
        const u16x4 ass = *(const u16x4*)(aoutR + 352 + c4);
        const f32x4 inn = *(const f32x4*)(innR + c4);
        const f32x4 xs = *(const f32x4*)(P.xs + gb);
        f32x4 o;
        #pragma unroll
        for (int j = 0; j < 4; ++j) o[j] = xs[j] + bf2f(asv[j]) * inn[j] + bf2f(ass[j]);
        *(f32x4*)(P.out + gb) = o;
    }
}

extern "C" void kernel_launch(void* const* d_in, const int* in_sizes, int n_in,
                              void* d_out, int out_size, void* d_ws, size_t ws_size,
                              hipStream_t stream)
{
    Ptrs P;
    P.xs  = (const float*)d_in[0];  P.xp  = (const float*)d_in[1];
    P.lng = (const float*)d_in[2];  P.lnb = (const float*)d_in[3];
    P.o3w = (const float*)d_in[4];  P.o3b = (const float*)d_in[5];
    P.Uw0 = (const float*)d_in[6];  P.Uw1 = (const float*)d_in[7];
    P.Uw2 = (const float*)d_in[8];  P.Ub0 = (const float*)d_in[9];
    P.Vw0 = (const float*)d_in[10]; P.Vw1 = (const float*)d_in[11];
    P.Vw2 = (const float*)d_in[12]; P.Vb0 = (const float*)d_in[13];
    P.dw  = (const float*)d_in[14]; P.w1  = (const float*)d_in[15];
    P.b1  = (const float*)d_in[16]; P.w2  = (const float*)d_in[17];
    P.b2  = (const float*)d_in[18];
    P.ws  = (const u16*)d_ws;
    P.out = (float*)d_out;

    const bool packed = (ws_size >= (size_t)PACK_TOT * sizeof(u16));
    if (packed) {
        pack_weights<<<(PACK_TOT + 255) / 256, 256, 0, stream>>>(P, (u16*)d_ws);
        xpainn_main<true><<<NBLK, NTHR, 0, stream>>>(P);
    } else {
        xpainn_main<false><<<NBLK, NTHR, 0, stream>>>(P);
    }
}